// Round 1
// baseline (341.215 us; speedup 1.0000x reference)
//
#include <hip/hip_runtime.h>
#include <hip/hip_bf16.h>

#define B_ 8
#define S_ 1024
#define U_ 1024
#define H_ 16
#define DK_ 64
#define M_ (B_*S_)   // 8192

typedef __attribute__((ext_vector_type(8))) short short8;
typedef __attribute__((ext_vector_type(4))) float f32x4;

__device__ inline ushort f2b(float x) {
  union { float f; unsigned u; } v; v.f = x;
  unsigned r = (v.u + 0x7FFFu + ((v.u >> 16) & 1u)) >> 16;
  return (ushort)r;
}

// ---------------- pack query fp32 -> bf16 ----------------
__global__ __launch_bounds__(256) void pack_x_kern(const float* __restrict__ X,
                                                   ushort* __restrict__ Xb) {
  int idx = blockIdx.x * 256 + threadIdx.x;   // 1M threads, 8 floats each
  const float4* src = (const float4*)X + (size_t)idx * 2;
  float4 a = src[0], b = src[1];
  ushort r[8];
  r[0]=f2b(a.x); r[1]=f2b(a.y); r[2]=f2b(a.z); r[3]=f2b(a.w);
  r[4]=f2b(b.x); r[5]=f2b(b.y); r[6]=f2b(b.z); r[7]=f2b(b.w);
  *(uint4*)(Xb + (size_t)idx*8) = *(uint4*)r;
}

// ---------------- pack weights (transpose to [n][k], bf16) ----------------
__global__ __launch_bounds__(256) void pack_w_kern(
    const float* __restrict__ Wq, const float* __restrict__ Wk, const float* __restrict__ Wv,
    const float* __restrict__ bq, const float* __restrict__ bk, const float* __restrict__ bv,
    const float* __restrict__ Wo,
    ushort* __restrict__ Wqkv, float* __restrict__ Bqkv, ushort* __restrict__ Wob)
{
  __shared__ ushort tile[64*65];
  const int t = threadIdx.x;
  const int bid = blockIdx.x;
  if (bid < 768) {
    // Wq/Wk/Wv: [h][k][d] -> Wqkv[n=p*1024+h*64+d][k]
    int p = bid >> 8, rem = bid & 255;
    int h = rem >> 4, kc = rem & 15, k0 = kc*64;
    const float* Wsrc = (p==0) ? Wq : ((p==1) ? Wk : Wv);
    #pragma unroll
    for (int i = 0; i < 16; ++i) {
      int e = t + i*256;                 // 0..4095
      int r = e >> 6, d = e & 63;        // r = k-local, d fast -> coalesced
      tile[d*65 + r] = f2b(Wsrc[h*65536 + (k0+r)*64 + d]);
    }
    __syncthreads();
    #pragma unroll
    for (int i = 0; i < 16; ++i) {
      int e = t + i*256;
      int d = e >> 6, r = e & 63;        // r fast -> coalesced write
      Wqkv[(size_t)(p*1024 + h*64 + d)*1024 + k0 + r] = tile[d*65 + r];
    }
    if (kc == 0 && t < 64) {
      const float* bsrc = (p==0) ? bq : ((p==1) ? bk : bv);
      Bqkv[p*1024 + h*64 + t] = bsrc[h*64 + t];
    }
  } else {
    // Wo: [k][n] -> Wob[n][k]
    int b2 = bid - 768;                  // 0..255
    int nc = b2 >> 4, kc = b2 & 15;
    int n0 = nc*64, k0 = kc*64;
    #pragma unroll
    for (int i = 0; i < 16; ++i) {
      int e = t + i*256;
      int r = e >> 6, d = e & 63;        // d over n (fast) -> coalesced read
      tile[d*65 + r] = f2b(Wo[(size_t)(k0+r)*1024 + n0 + d]);
    }
    __syncthreads();
    #pragma unroll
    for (int i = 0; i < 16; ++i) {
      int e = t + i*256;
      int d = e >> 6, r = e & 63;
      Wob[(size_t)(n0+d)*1024 + k0 + r] = tile[d*65 + r];
    }
  }
}

// ---------------- GEMM: C[m][n] = A[m][:] . Bw[n][:] + bias[n] ----------------
// MODE 0: QKV projection, N=3072, epilogue scatters bf16 into Q/K/V (B,H,S,DK),
//         q scaled by 1/sqrt(DK).
// MODE 1: output projection, N=1024, fp32 out.
template<int MODE>
__global__ __launch_bounds__(256) void gemm_kern(
    const ushort* __restrict__ A,   // [M][1024] bf16 row-major
    const ushort* __restrict__ Bw,  // [N][1024] bf16 (k contiguous)
    const float* __restrict__ bias, // [N]
    ushort* __restrict__ Qb, ushort* __restrict__ Kb, ushort* __restrict__ Vb,
    float* __restrict__ outF)
{
  __shared__ __align__(16) ushort As[128*32];
  __shared__ __align__(16) ushort Bs[128*32];
  const int m0 = blockIdx.x * 128;
  const int n0 = blockIdx.y * 128;
  const int t = threadIdx.x;
  const int l = t & 63, w = t >> 6;
  const int wr = w >> 1, wc = w & 1;

  f32x4 acc[4][4];
  #pragma unroll
  for (int i=0;i<4;i++)
    #pragma unroll
    for (int j=0;j<4;j++) acc[i][j] = (f32x4)0.0f;

  for (int kk = 0; kk < 1024; kk += 32) {
    __syncthreads();
    #pragma unroll
    for (int pass = 0; pass < 2; ++pass) {
      int c = t + pass*256;              // 0..511 chunks of 16B
      int row = c >> 2, cc = c & 3;
      *(uint4*)&As[row*32 + cc*8] = *(const uint4*)&A[(size_t)(m0+row)*1024 + kk + cc*8];
      *(uint4*)&Bs[row*32 + cc*8] = *(const uint4*)&Bw[(size_t)(n0+row)*1024 + kk + cc*8];
    }
    __syncthreads();
    short8 af[4], bf[4];
    #pragma unroll
    for (int i=0;i<4;i++) {
      af[i] = *(const short8*)&As[(wr*64 + i*16 + (l&15))*32 + 8*(l>>4)];
      bf[i] = *(const short8*)&Bs[(wc*64 + i*16 + (l&15))*32 + 8*(l>>4)];
    }
    #pragma unroll
    for (int i=0;i<4;i++)
      #pragma unroll
      for (int j=0;j<4;j++)
        acc[i][j] = __builtin_amdgcn_mfma_f32_16x16x32_bf16(af[i], bf[j], acc[i][j], 0, 0, 0);
  }

  #pragma unroll
  for (int i=0;i<4;i++) {
    int rbase = m0 + wr*64 + i*16 + ((l>>4)<<2);
    #pragma unroll
    for (int j=0;j<4;j++) {
      int col = n0 + wc*64 + j*16 + (l&15);
      float bv = bias[col];
      if (MODE == 0) {
        int p = col >> 10, h = (col >> 6) & 15, d = col & 63;
        ushort* dst = (p==0) ? Qb : ((p==1) ? Kb : Vb);
        float sc = (p==0) ? 0.125f : 1.0f;
        #pragma unroll
        for (int r=0;r<4;r++) {
          int m = rbase + r;
          int b = m >> 10, s = m & 1023;
          dst[(((size_t)(b*16 + h))*1024 + s)*64 + d] = f2b((acc[i][j][r] + bv) * sc);
        }
      } else {
        #pragma unroll
        for (int r=0;r<4;r++) {
          int m = rbase + r;
          outF[(size_t)m*1024 + col] = acc[i][j][r] + bv;
        }
      }
    }
  }
}

// ---------------- causal flash attention ----------------
// grid: (S/64, B*H). 4 waves, each owns 16 q-rows. K/V tiles of 32.
__global__ __launch_bounds__(256) void attn_kern(
    const ushort* __restrict__ Qb, const ushort* __restrict__ Kb,
    const ushort* __restrict__ Vb, ushort* __restrict__ Ob)
{
  const int qt = blockIdx.x;       // 0..15
  const int bh = blockIdx.y;       // 0..127 = b*16+h
  const int t = threadIdx.x, l = t & 63, w = t >> 6;

  __shared__ __align__(16) ushort Ks[32*64];   // [kv][d]
  __shared__ __align__(16) ushort Vt[64*32];   // [d][kv] (transposed)
  __shared__ __align__(16) ushort Pb[4][16*32];

  const ushort* Qp = Qb + (size_t)bh*S_*DK_;
  const ushort* Kp = Kb + (size_t)bh*S_*DK_;
  const ushort* Vp = Vb + (size_t)bh*S_*DK_;

  const int qrow_a = qt*64 + w*16 + (l&15);
  short8 qf0 = *(const short8*)&Qp[(size_t)qrow_a*64 + 8*(l>>4)];
  short8 qf1 = *(const short8*)&Qp[(size_t)qrow_a*64 + 32 + 8*(l>>4)];

  f32x4 accO[4];
  #pragma unroll
  for (int dt=0; dt<4; ++dt) accO[dt] = (f32x4)0.0f;
  float mR[4], lR[4];
  #pragma unroll
  for (int j=0;j<4;j++) { mR[j] = -1e30f; lR[j] = 0.0f; }

  const int nk = qt*2 + 2;
  for (int kt = 0; kt < nk; ++kt) {
    const int kb = kt*32;
    __syncthreads();
    {
      int row = t >> 3, c8 = (t & 7) << 3;
      uint4 kv = *(const uint4*)&Kp[(size_t)(kb+row)*64 + c8];
      *(uint4*)&Ks[row*64 + c8] = kv;
      uint4 vv = *(const uint4*)&Vp[(size_t)(kb+row)*64 + c8];
      ushort tmp[8]; *(uint4*)tmp = vv;
      #pragma unroll
      for (int i=0;i<8;i++) Vt[(c8+i)*32 + row] = tmp[i];
    }
    __syncthreads();

    f32x4 sacc[2];
    sacc[0] = (f32x4)0.0f; sacc[1] = (f32x4)0.0f;
    #pragma unroll
    for (int ct=0; ct<2; ++ct) {
      short8 kf0 = *(const short8*)&Ks[(ct*16 + (l&15))*64 + 8*(l>>4)];
      short8 kf1 = *(const short8*)&Ks[(ct*16 + (l&15))*64 + 32 + 8*(l>>4)];
      sacc[ct] = __builtin_amdgcn_mfma_f32_16x16x32_bf16(qf0, kf0, sacc[ct], 0,0,0);
      sacc[ct] = __builtin_amdgcn_mfma_f32_16x16x32_bf16(qf1, kf1, sacc[ct], 0,0,0);
    }

    const int qg0 = qt*64 + w*16 + ((l>>4)<<2);
    float p0[4], p1[4], mx[4];
    #pragma unroll
    for (int j=0;j<4;j++) {
      float v0 = sacc[0][j], v1 = sacc[1][j];
      int kv0 = kb + (l&15), kv1 = kb + 16 + (l&15);
      int qg = qg0 + j;
      if (kv0 > qg) v0 = -1e30f;
      if (kv1 > qg) v1 = -1e30f;
      p0[j] = v0; p1[j] = v1;
      mx[j] = fmaxf(v0, v1);
    }
    #pragma unroll
    for (int d=1; d<16; d<<=1) {
      #pragma unroll
      for (int j=0;j<4;j++) mx[j] = fmaxf(mx[j], __shfl_xor(mx[j], d));
    }
    float corr[4], rs[4];
    #pragma unroll
    for (int j=0;j<4;j++) {
      float mn = fmaxf(mR[j], mx[j]);
      corr[j] = __expf(mR[j] - mn);
      mR[j] = mn;
      p0[j] = __expf(p0[j] - mn);
      p1[j] = __expf(p1[j] - mn);
      rs[j] = p0[j] + p1[j];
    }
    #pragma unroll
    for (int d=1; d<16; d<<=1) {
      #pragma unroll
      for (int j=0;j<4;j++) rs[j] += __shfl_xor(rs[j], d);
    }
    #pragma unroll
    for (int j=0;j<4;j++) lR[j] = lR[j]*corr[j] + rs[j];
    #pragma unroll
    for (int dt=0; dt<4; ++dt)
      #pragma unroll
      for (int j=0;j<4;j++) accO[dt][j] *= corr[j];

    ushort* Pw = &Pb[w][0];
    #pragma unroll
    for (int j=0;j<4;j++) {
      int q = ((l>>4)<<2) + j;
      Pw[q*32 + (l&15)]      = f2b(p0[j]);
      Pw[q*32 + 16 + (l&15)] = f2b(p1[j]);
    }
    short8 pf = *(const short8*)&Pw[(l&15)*32 + 8*(l>>4)];
    #pragma unroll
    for (int dt=0; dt<4; ++dt) {
      short8 vf = *(const short8*)&Vt[(dt*16 + (l&15))*32 + 8*(l>>4)];
      accO[dt] = __builtin_amdgcn_mfma_f32_16x16x32_bf16(pf, vf, accO[dt], 0,0,0);
    }
  }

  const int b = bh >> 4, h = bh & 15;
  #pragma unroll
  for (int j=0;j<4;j++) {
    float inv = 1.0f / lR[j];
    int qg = qt*64 + w*16 + ((l>>4)<<2) + j;
    size_t base = ((size_t)(b*1024 + qg))*1024 + h*64;
    #pragma unroll
    for (int dt=0; dt<4; ++dt)
      Ob[base + dt*16 + (l&15)] = f2b(accO[dt][j] * inv);
  }
}

extern "C" void kernel_launch(void* const* d_in, const int* in_sizes, int n_in,
                              void* d_out, int out_size, void* d_ws, size_t ws_size,
                              hipStream_t stream) {
  const float* query = (const float*)d_in[0];
  // d_in[1]=key, d_in[2]=value, d_in[3]=mask: unused (reference projects q,k,v
  // all from `query`; mask is causal tril, hardcoded).
  const float* Wq = (const float*)d_in[4];
  const float* bq = (const float*)d_in[5];
  const float* Wk = (const float*)d_in[6];
  const float* bk = (const float*)d_in[7];
  const float* Wv = (const float*)d_in[8];
  const float* bv = (const float*)d_in[9];
  const float* Wo = (const float*)d_in[10];
  const float* bo = (const float*)d_in[11];

  char* wsb = (char*)d_ws;
  ushort* Xb   = (ushort*)(wsb);                  // 16 MB
  ushort* Wqkv = (ushort*)(wsb + 16777216);       // 6 MB
  float*  Bqkv = (float*) (wsb + 23068672);       // 12 KB
  ushort* Wob  = (ushort*)(wsb + 23080960);       // 2 MB
  ushort* Qb   = (ushort*)(wsb + 25178112);       // 16 MB
  ushort* Kb   = (ushort*)(wsb + 41955328);       // 16 MB
  ushort* Vb   = (ushort*)(wsb + 58732544);       // 16 MB
  ushort* Ob   = (ushort*)(wsb + 75509760);       // 16 MB

  hipLaunchKernelGGL(pack_x_kern, dim3(4096), dim3(256), 0, stream, query, Xb);
  hipLaunchKernelGGL(pack_w_kern, dim3(1024), dim3(256), 0, stream,
                     Wq, Wk, Wv, bq, bk, bv, Wo, Wqkv, Bqkv, Wob);
  hipLaunchKernelGGL(gemm_kern<0>, dim3(64, 24), dim3(256), 0, stream,
                     Xb, Wqkv, Bqkv, Qb, Kb, Vb, (float*)nullptr);
  hipLaunchKernelGGL(attn_kern, dim3(16, 128), dim3(256), 0, stream, Qb, Kb, Vb, Ob);
  hipLaunchKernelGGL(gemm_kern<1>, dim3(64, 8), dim3(256), 0, stream,
                     Ob, Wob, bo, (ushort*)nullptr, (ushort*)nullptr, (ushort*)nullptr,
                     (float*)d_out);
}

// Round 2
// 315.743 us; speedup vs baseline: 1.0807x; 1.0807x over previous
//
#include <hip/hip_runtime.h>
#include <hip/hip_bf16.h>

#define B_ 8
#define S_ 1024
#define U_ 1024
#define H_ 16
#define DK_ 64
#define M_ (B_*S_)   // 8192

typedef __attribute__((ext_vector_type(8))) short short8;
typedef __attribute__((ext_vector_type(4))) float f32x4;

__device__ inline ushort f2b(float x) {
  union { float f; unsigned u; } v; v.f = x;
  unsigned r = (v.u + 0x7FFFu + ((v.u >> 16) & 1u)) >> 16;
  return (ushort)r;
}

__device__ inline void gld16(const ushort* g, ushort* l) {
  __builtin_amdgcn_global_load_lds((__attribute__((address_space(1))) void*)(g),
                                   (__attribute__((address_space(3))) void*)(l),
                                   16, 0, 0);
}

// ---------------- pack query fp32 -> bf16 ----------------
__global__ __launch_bounds__(256) void pack_x_kern(const float* __restrict__ X,
                                                   ushort* __restrict__ Xb) {
  int idx = blockIdx.x * 256 + threadIdx.x;
  const float4* src = (const float4*)X + (size_t)idx * 2;
  float4 a = src[0], b = src[1];
  ushort r[8];
  r[0]=f2b(a.x); r[1]=f2b(a.y); r[2]=f2b(a.z); r[3]=f2b(a.w);
  r[4]=f2b(b.x); r[5]=f2b(b.y); r[6]=f2b(b.z); r[7]=f2b(b.w);
  *(uint4*)(Xb + (size_t)idx*8) = *(uint4*)r;
}

// ---------------- pack weights (transpose to [n][k], bf16) ----------------
__global__ __launch_bounds__(256) void pack_w_kern(
    const float* __restrict__ Wq, const float* __restrict__ Wk, const float* __restrict__ Wv,
    const float* __restrict__ bq, const float* __restrict__ bk, const float* __restrict__ bv,
    const float* __restrict__ Wo,
    ushort* __restrict__ Wqkv, float* __restrict__ Bqkv, ushort* __restrict__ Wob)
{
  __shared__ ushort tile[64*65];
  const int t = threadIdx.x;
  const int bid = blockIdx.x;
  if (bid < 768) {
    int p = bid >> 8, rem = bid & 255;
    int h = rem >> 4, kc = rem & 15, k0 = kc*64;
    const float* Wsrc = (p==0) ? Wq : ((p==1) ? Wk : Wv);
    #pragma unroll
    for (int i = 0; i < 16; ++i) {
      int e = t + i*256;
      int r = e >> 6, d = e & 63;
      tile[d*65 + r] = f2b(Wsrc[h*65536 + (k0+r)*64 + d]);
    }
    __syncthreads();
    #pragma unroll
    for (int i = 0; i < 16; ++i) {
      int e = t + i*256;
      int d = e >> 6, r = e & 63;
      Wqkv[(size_t)(p*1024 + h*64 + d)*1024 + k0 + r] = tile[d*65 + r];
    }
    if (kc == 0 && t < 64) {
      const float* bsrc = (p==0) ? bq : ((p==1) ? bk : bv);
      Bqkv[p*1024 + h*64 + t] = bsrc[h*64 + t];
    }
  } else {
    int b2 = bid - 768;
    int nc = b2 >> 4, kc = b2 & 15;
    int n0 = nc*64, k0 = kc*64;
    #pragma unroll
    for (int i = 0; i < 16; ++i) {
      int e = t + i*256;
      int r = e >> 6, d = e & 63;
      tile[d*65 + r] = f2b(Wo[(size_t)(k0+r)*1024 + n0 + d]);
    }
    __syncthreads();
    #pragma unroll
    for (int i = 0; i < 16; ++i) {
      int e = t + i*256;
      int d = e >> 6, r = e & 63;
      Wob[(size_t)(n0+d)*1024 + k0 + r] = tile[d*65 + r];
    }
  }
}

// ---------------- GEMM with global_load_lds staging ----------------
// MODE 0: QKV projection, N=3072, scatters bf16 into Q/K/V (B,H,S,DK);
//         q scaled by 0.125*log2(e) (log2-domain softmax downstream).
// MODE 1: output projection, N=1024, fp32 out.
template<int MODE>
__global__ __launch_bounds__(256) void gemm_kern(
    const ushort* __restrict__ A,
    const ushort* __restrict__ Bw,
    const float* __restrict__ bias,
    ushort* __restrict__ Qb, ushort* __restrict__ Kb, ushort* __restrict__ Vb,
    float* __restrict__ outF)
{
  __shared__ __align__(16) ushort As[128*32];
  __shared__ __align__(16) ushort Bs[128*32];
  const int m0 = blockIdx.x * 128;
  const int n0 = blockIdx.y * 128;
  const int t = threadIdx.x;
  const int l = t & 63, w = t >> 6;
  const int wr = w >> 1, wc = w & 1;

  f32x4 acc[4][4];
  #pragma unroll
  for (int i=0;i<4;i++)
    #pragma unroll
    for (int j=0;j<4;j++) acc[i][j] = (f32x4)0.0f;

  for (int kk = 0; kk < 1024; kk += 32) {
    __syncthreads();
    #pragma unroll
    for (int pass = 0; pass < 2; ++pass) {
      int c = pass*256 + t;
      int row = c >> 2, cc = c & 3;
      int cw = pass*256 + w*64;          // wave-uniform chunk base
      gld16(&A[(size_t)(m0+row)*1024 + kk + cc*8],  &As[cw*8]);
      gld16(&Bw[(size_t)(n0+row)*1024 + kk + cc*8], &Bs[cw*8]);
    }
    __syncthreads();
    short8 af[4], bf[4];
    #pragma unroll
    for (int i=0;i<4;i++) {
      af[i] = *(const short8*)&As[(wr*64 + i*16 + (l&15))*32 + 8*(l>>4)];
      bf[i] = *(const short8*)&Bs[(wc*64 + i*16 + (l&15))*32 + 8*(l>>4)];
    }
    #pragma unroll
    for (int i=0;i<4;i++)
      #pragma unroll
      for (int j=0;j<4;j++)
        acc[i][j] = __builtin_amdgcn_mfma_f32_16x16x32_bf16(af[i], bf[j], acc[i][j], 0, 0, 0);
  }

  #pragma unroll
  for (int i=0;i<4;i++) {
    int rbase = m0 + wr*64 + i*16 + ((l>>4)<<2);
    #pragma unroll
    for (int j=0;j<4;j++) {
      int col = n0 + wc*64 + j*16 + (l&15);
      float bv = bias[col];
      if (MODE == 0) {
        int p = col >> 10, h = (col >> 6) & 15, d = col & 63;
        ushort* dst = (p==0) ? Qb : ((p==1) ? Kb : Vb);
        float sc = (p==0) ? 0.18033688011112042f : 1.0f;   // 0.125 * log2(e)
        #pragma unroll
        for (int r=0;r<4;r++) {
          int m = rbase + r;
          int b = m >> 10, s = m & 1023;
          dst[(((size_t)(b*16 + h))*1024 + s)*64 + d] = f2b((acc[i][j][r] + bv) * sc);
        }
      } else {
        #pragma unroll
        for (int r=0;r<4;r++) {
          int m = rbase + r;
          outF[(size_t)m*1024 + col] = acc[i][j][r] + bv;
        }
      }
    }
  }
}

// ---------------- causal flash attention (QBLK=256, KVBLK=32, dbuf) ----------
// grid: 512 blocks, 4 waves. Wave w owns q-fragments rb(qf)=qt*256+qf*64+w*16
// (interleaved -> balanced causal work). Scores arrive in log2 domain.
__global__ __launch_bounds__(256) void attn_kern(
    const ushort* __restrict__ Qb, const ushort* __restrict__ Kb,
    const ushort* __restrict__ Vb, ushort* __restrict__ Ob)
{
  const int b0 = blockIdx.x;
  const int bh = b0 >> 2;
  const int qtr = b0 & 3;
  const int qt = (bh & 1) ? (3 - qtr) : qtr;   // mix long/short blocks
  const int t = threadIdx.x, l = t & 63, w = t >> 6;
  const int grp = l >> 4, li = l & 15;

  __shared__ __align__(16) ushort Ks[2][32*72];   // [kv][d] stride 72
  __shared__ __align__(16) ushort Vt[2][64*40];   // [d][kv] stride 40
  __shared__ __align__(16) ushort Pb[4][64*40];   // per-wave [q][kv] stride 40

  const ushort* Qp = Qb + (size_t)bh*65536;
  const ushort* Kp = Kb + (size_t)bh*65536;
  const ushort* Vp = Vb + (size_t)bh*65536;

  short8 qA[4][2];
  #pragma unroll
  for (int qf=0; qf<4; ++qf) {
    int rb = qt*256 + qf*64 + w*16;
    qA[qf][0] = *(const short8*)&Qp[(size_t)(rb+li)*64 + grp*8];
    qA[qf][1] = *(const short8*)&Qp[(size_t)(rb+li)*64 + 32 + grp*8];
  }

  f32x4 accO[4][4];
  float mR[4][4], lR[4][4];
  #pragma unroll
  for (int qf=0;qf<4;++qf) {
    #pragma unroll
    for (int j=0;j<4;++j) { mR[qf][j] = -1e30f; lR[qf][j] = 0.0f; }
    #pragma unroll
    for (int df=0;df<4;++df) accO[qf][df] = (f32x4)0.0f;
  }

  const int krow = t >> 3,  kc8 = (t & 7) * 8;   // K stage: coalesced
  const int vrow = t & 31,  vd8 = (t >> 5) * 8;  // V stage: conflict-free LDS
  const int nk = (qt + 1) * 8;
  const int rb3 = qt*256 + 192 + w*16;

  { // stage tile 0
    uint4 kv = *(const uint4*)&Kp[(size_t)krow*64 + kc8];
    uint4 vv = *(const uint4*)&Vp[(size_t)vrow*64 + vd8];
    *(uint4*)&Ks[0][krow*72 + kc8] = kv;
    ushort tmp[8]; *(uint4*)tmp = vv;
    #pragma unroll
    for (int s2=0;s2<8;++s2) Vt[0][(vd8+s2)*40 + vrow] = tmp[s2];
  }
  __syncthreads();

  for (int kt = 0; kt < nk; ++kt) {
    const int cur = kt & 1, kb = kt*32;
    uint4 kreg, vreg;
    const bool pre = (kt+1 < nk);
    if (pre) {   // T14: issue next-tile loads before compute
      kreg = *(const uint4*)&Kp[(size_t)((kt+1)*32+krow)*64 + kc8];
      vreg = *(const uint4*)&Vp[(size_t)((kt+1)*32+vrow)*64 + vd8];
    }

    if (kb < rb3 + 16) {            // wave has >=1 active fragment
      short8 kB[2][2], vf[4];
      #pragma unroll
      for (int kf=0;kf<2;++kf) {
        kB[kf][0] = *(const short8*)&Ks[cur][(kf*16+li)*72 + grp*8];
        kB[kf][1] = *(const short8*)&Ks[cur][(kf*16+li)*72 + 32 + grp*8];
      }
      #pragma unroll
      for (int df=0;df<4;++df)
        vf[df] = *(const short8*)&Vt[cur][(df*16+li)*40 + grp*8];

      ushort* Pw = &Pb[w][0];
      #pragma unroll
      for (int qf=0; qf<4; ++qf) {
        const int rb = qt*256 + qf*64 + w*16;
        if (kb >= rb + 16) continue;          // fully masked fragment
        f32x4 s0 = (f32x4)0.0f, s1 = (f32x4)0.0f;
        s0 = __builtin_amdgcn_mfma_f32_16x16x32_bf16(qA[qf][0], kB[0][0], s0, 0,0,0);
        s0 = __builtin_amdgcn_mfma_f32_16x16x32_bf16(qA[qf][1], kB[0][1], s0, 0,0,0);
        s1 = __builtin_amdgcn_mfma_f32_16x16x32_bf16(qA[qf][0], kB[1][0], s1, 0,0,0);
        s1 = __builtin_amdgcn_mfma_f32_16x16x32_bf16(qA[qf][1], kB[1][1], s1, 0,0,0);

        float p0[4], p1[4], mx[4];
        const bool dm = (kb + 31 > rb);       // diagonal tile -> mask
        #pragma unroll
        for (int j=0;j<4;++j) {
          float v0 = s0[j], v1 = s1[j];
          if (dm) {
            int q = rb + grp*4 + j;
            if (kb + li > q)      v0 = -1e9f;
            if (kb + 16 + li > q) v1 = -1e9f;
          }
          p0[j]=v0; p1[j]=v1; mx[j]=fmaxf(v0,v1);
        }
        #pragma unroll
        for (int d2=1; d2<16; d2<<=1)
          #pragma unroll
          for (int j=0;j<4;++j) mx[j] = fmaxf(mx[j], __shfl_xor(mx[j], d2));

        float dmax = fmaxf(fmaxf(mx[0]-mR[qf][0], mx[1]-mR[qf][1]),
                           fmaxf(mx[2]-mR[qf][2], mx[3]-mR[qf][3]));
        const bool resc = __any(dmax > 8.0f);  // T13 defer-max (log2 units)
        if (resc) {
          #pragma unroll
          for (int j=0;j<4;++j) {
            float mn = fmaxf(mR[qf][j], mx[j]);
            float corr = __builtin_amdgcn_exp2f(mR[qf][j] - mn);
            mR[qf][j] = mn;
            lR[qf][j] *= corr;
            #pragma unroll
            for (int df=0;df<4;++df) accO[qf][df][j] *= corr;
          }
        }
        float rs[4];
        #pragma unroll
        for (int j=0;j<4;++j) {
          p0[j] = __builtin_amdgcn_exp2f(p0[j] - mR[qf][j]);
          p1[j] = __builtin_amdgcn_exp2f(p1[j] - mR[qf][j]);
          rs[j] = p0[j] + p1[j];
        }
        #pragma unroll
        for (int d2=1; d2<16; d2<<=1)
          #pragma unroll
          for (int j=0;j<4;++j) rs[j] += __shfl_xor(rs[j], d2);
        #pragma unroll
        for (int j=0;j<4;++j) lR[qf][j] += rs[j];

        #pragma unroll
        for (int j=0;j<4;++j) {
          int q = qf*16 + grp*4 + j;
          Pw[q*40 + li]      = f2b(p0[j]);
          Pw[q*40 + 16 + li] = f2b(p1[j]);
        }
        short8 pf = *(const short8*)&Pw[(qf*16 + li)*40 + grp*8];
        #pragma unroll
        for (int df=0;df<4;++df)
          accO[qf][df] = __builtin_amdgcn_mfma_f32_16x16x32_bf16(pf, vf[df], accO[qf][df], 0,0,0);
      }
    }

    if (pre) {   // write next tile into other buffer
      *(uint4*)&Ks[cur^1][krow*72 + kc8] = kreg;
      ushort tmp[8]; *(uint4*)tmp = vreg;
      #pragma unroll
      for (int s2=0;s2<8;++s2) Vt[cur^1][(vd8+s2)*40 + vrow] = tmp[s2];
    }
    __syncthreads();
  }

  const int b = bh >> 4, h = bh & 15;
  #pragma unroll
  for (int qf=0;qf<4;++qf) {
    #pragma unroll
    for (int j=0;j<4;++j) {
      int qg = qt*256 + qf*64 + w*16 + grp*4 + j;
      float inv = 1.0f / lR[qf][j];
      size_t base = ((size_t)(b*1024 + qg))*1024 + h*64;
      #pragma unroll
      for (int df=0;df<4;++df)
        Ob[base + df*16 + li] = f2b(accO[qf][df][j] * inv);
    }
  }
}

extern "C" void kernel_launch(void* const* d_in, const int* in_sizes, int n_in,
                              void* d_out, int out_size, void* d_ws, size_t ws_size,
                              hipStream_t stream) {
  const float* query = (const float*)d_in[0];
  const float* Wq = (const float*)d_in[4];
  const float* bq = (const float*)d_in[5];
  const float* Wk = (const float*)d_in[6];
  const float* bk = (const float*)d_in[7];
  const float* Wv = (const float*)d_in[8];
  const float* bv = (const float*)d_in[9];
  const float* Wo = (const float*)d_in[10];
  const float* bo = (const float*)d_in[11];

  char* wsb = (char*)d_ws;
  ushort* Xb   = (ushort*)(wsb);                  // 16 MB
  ushort* Wqkv = (ushort*)(wsb + 16777216);       // 6 MB
  float*  Bqkv = (float*) (wsb + 23068672);       // 12 KB
  ushort* Wob  = (ushort*)(wsb + 23080960);       // 2 MB
  ushort* Qb   = (ushort*)(wsb + 25178112);       // 16 MB
  ushort* Kb   = (ushort*)(wsb + 41955328);       // 16 MB
  ushort* Vb   = (ushort*)(wsb + 58732544);       // 16 MB
  ushort* Ob   = (ushort*)(wsb + 75509760);       // 16 MB

  hipLaunchKernelGGL(pack_x_kern, dim3(4096), dim3(256), 0, stream, query, Xb);
  hipLaunchKernelGGL(pack_w_kern, dim3(1024), dim3(256), 0, stream,
                     Wq, Wk, Wv, bq, bk, bv, Wo, Wqkv, Bqkv, Wob);
  hipLaunchKernelGGL(gemm_kern<0>, dim3(64, 24), dim3(256), 0, stream,
                     Xb, Wqkv, Bqkv, Qb, Kb, Vb, (float*)nullptr);
  hipLaunchKernelGGL(attn_kern, dim3(512), dim3(256), 0, stream, Qb, Kb, Vb, Ob);
  hipLaunchKernelGGL(gemm_kern<1>, dim3(64, 8), dim3(256), 0, stream,
                     Ob, Wob, bo, (ushort*)nullptr, (ushort*)nullptr, (ushort*)nullptr,
                     (float*)d_out);
}

// Round 4
// 181.771 us; speedup vs baseline: 1.8772x; 1.7370x over previous
//
#include <hip/hip_runtime.h>
#include <hip/hip_bf16.h>

#define B_ 8
#define S_ 1024
#define U_ 1024
#define H_ 16
#define DK_ 64

typedef __attribute__((ext_vector_type(8))) short short8;
typedef __attribute__((ext_vector_type(4))) float f32x4;
typedef __attribute__((ext_vector_type(16))) float f32x16;

__device__ inline ushort f2b(float x) {
  union { float f; unsigned u; } v; v.f = x;
  unsigned r = (v.u + 0x7FFFu + ((v.u >> 16) & 1u)) >> 16;
  return (ushort)r;
}
__device__ inline unsigned pk2(float lo, float hi) {
  return (unsigned)f2b(lo) | ((unsigned)f2b(hi) << 16);
}

__device__ inline void gld16(const ushort* g, ushort* l) {
  __builtin_amdgcn_global_load_lds((__attribute__((address_space(1))) void*)(g),
                                   (__attribute__((address_space(3))) void*)(l),
                                   16, 0, 0);
}

// ---------------- pack query fp32 -> bf16 ----------------
__global__ __launch_bounds__(256) void pack_x_kern(const float* __restrict__ X,
                                                   ushort* __restrict__ Xb) {
  int idx = blockIdx.x * 256 + threadIdx.x;
  const float4* src = (const float4*)X + (size_t)idx * 2;
  float4 a = src[0], b = src[1];
  ushort r[8];
  r[0]=f2b(a.x); r[1]=f2b(a.y); r[2]=f2b(a.z); r[3]=f2b(a.w);
  r[4]=f2b(b.x); r[5]=f2b(b.y); r[6]=f2b(b.z); r[7]=f2b(b.w);
  *(uint4*)(Xb + (size_t)idx*8) = *(uint4*)r;
}

// ---------------- pack weights (transpose to [n][k], bf16) ----------------
__global__ __launch_bounds__(256) void pack_w_kern(
    const float* __restrict__ Wq, const float* __restrict__ Wk, const float* __restrict__ Wv,
    const float* __restrict__ bq, const float* __restrict__ bk, const float* __restrict__ bv,
    const float* __restrict__ Wo,
    ushort* __restrict__ Wqkv, float* __restrict__ Bqkv, ushort* __restrict__ Wob)
{
  __shared__ ushort tile[64*65];
  const int t = threadIdx.x;
  const int bid = blockIdx.x;
  if (bid < 768) {
    int p = bid >> 8, rem = bid & 255;
    int h = rem >> 4, kc = rem & 15, k0 = kc*64;
    const float* Wsrc = (p==0) ? Wq : ((p==1) ? Wk : Wv);
    #pragma unroll
    for (int i = 0; i < 16; ++i) {
      int e = t + i*256;
      int r = e >> 6, d = e & 63;
      tile[d*65 + r] = f2b(Wsrc[h*65536 + (k0+r)*64 + d]);
    }
    __syncthreads();
    #pragma unroll
    for (int i = 0; i < 16; ++i) {
      int e = t + i*256;
      int d = e >> 6, r = e & 63;
      Wqkv[(size_t)(p*1024 + h*64 + d)*1024 + k0 + r] = tile[d*65 + r];
    }
    if (kc == 0 && t < 64) {
      const float* bsrc = (p==0) ? bq : ((p==1) ? bk : bv);
      Bqkv[p*1024 + h*64 + t] = bsrc[h*64 + t];
    }
  } else {
    int b2 = bid - 768;
    int nc = b2 >> 4, kc = b2 & 15;
    int n0 = nc*64, k0 = kc*64;
    #pragma unroll
    for (int i = 0; i < 16; ++i) {
      int e = t + i*256;
      int r = e >> 6, d = e & 63;
      tile[d*65 + r] = f2b(Wo[(size_t)(k0+r)*1024 + n0 + d]);
    }
    __syncthreads();
    #pragma unroll
    for (int i = 0; i < 16; ++i) {
      int e = t + i*256;
      int d = e >> 6, r = e & 63;
      Wob[(size_t)(n0+d)*1024 + k0 + r] = tile[d*65 + r];
    }
  }
}

// ---------------- GEMM with global_load_lds staging ----------------
// MODE 0: QKV proj; Q scaled by 0.125*log2(e) into [bh][s][d]; K into [bh][s][d];
//         V written TRANSPOSED into Vt[bh][d][s].
// MODE 1: out proj, fp32.
template<int MODE>
__global__ __launch_bounds__(256) void gemm_kern(
    const ushort* __restrict__ A,
    const ushort* __restrict__ Bw,
    const float* __restrict__ bias,
    ushort* __restrict__ Qb, ushort* __restrict__ Kb, ushort* __restrict__ Vtb,
    float* __restrict__ outF)
{
  __shared__ __align__(16) ushort As[128*32];
  __shared__ __align__(16) ushort Bs[128*32];
  const int m0 = blockIdx.x * 128;
  const int n0 = blockIdx.y * 128;
  const int t = threadIdx.x;
  const int l = t & 63, w = t >> 6;
  const int wr = w >> 1, wc = w & 1;

  f32x4 acc[4][4];
  #pragma unroll
  for (int i=0;i<4;i++)
    #pragma unroll
    for (int j=0;j<4;j++) acc[i][j] = (f32x4)0.0f;

  for (int kk = 0; kk < 1024; kk += 32) {
    __syncthreads();
    #pragma unroll
    for (int pass = 0; pass < 2; ++pass) {
      int c = pass*256 + t;
      int row = c >> 2, cc = c & 3;
      int cw = pass*256 + w*64;
      gld16(&A[(size_t)(m0+row)*1024 + kk + cc*8],  &As[cw*8]);
      gld16(&Bw[(size_t)(n0+row)*1024 + kk + cc*8], &Bs[cw*8]);
    }
    __syncthreads();
    short8 af[4], bf[4];
    #pragma unroll
    for (int i=0;i<4;i++) {
      af[i] = *(const short8*)&As[(wr*64 + i*16 + (l&15))*32 + 8*(l>>4)];
      bf[i] = *(const short8*)&Bs[(wc*64 + i*16 + (l&15))*32 + 8*(l>>4)];
    }
    #pragma unroll
    for (int i=0;i<4;i++)
      #pragma unroll
      for (int j=0;j<4;j++)
        acc[i][j] = __builtin_amdgcn_mfma_f32_16x16x32_bf16(af[i], bf[j], acc[i][j], 0, 0, 0);
  }

  #pragma unroll
  for (int i=0;i<4;i++) {
    int rbase = m0 + wr*64 + i*16 + ((l>>4)<<2);
    #pragma unroll
    for (int j=0;j<4;j++) {
      int col = n0 + wc*64 + j*16 + (l&15);
      float bv = bias[col];
      if (MODE == 0) {
        int p = col >> 10, h = (col >> 6) & 15, d = col & 63;
        int b = rbase >> 10, s = rbase & 1023;
        if (p == 2) {          // V -> transposed [bh][d][s], 8B packed store
          ushort pk4[4];
          #pragma unroll
          for (int r=0;r<4;r++) pk4[r] = f2b(acc[i][j][r] + bv);
          *(uint2*)&Vtb[((size_t)((b*16+h)*64 + d))*1024 + s] = *(uint2*)pk4;
        } else {
          ushort* dst = (p==0) ? Qb : Kb;
          float sc = (p==0) ? 0.18033688011112042f : 1.0f;   // 0.125*log2(e)
          #pragma unroll
          for (int r=0;r<4;r++)
            dst[(((size_t)(b*16 + h))*1024 + s + r)*64 + d] = f2b((acc[i][j][r] + bv) * sc);
        }
      } else {
        #pragma unroll
        for (int r=0;r<4;r++)
          outF[(size_t)(rbase+r)*1024 + col] = acc[i][j][r] + bv;
      }
    }
  }
}

// ---------------- causal flash attention, wave-independent ----------------
// 1024 blocks x 256 thr; wave w handles q-tile {j,15-j,16+j,31-j}[w] of head bh.
// No __syncthreads. 32x32x16 MFMAs; swapped QK^T (S[kv][q]) and swapped PV
// (O[d][q]) so softmax state is per-lane scalar + one shfl_xor(32).
// Scores in log2 domain (scale folded into Q).
__global__ __launch_bounds__(256, 3) void attn_kern(
    const ushort* __restrict__ Qb, const ushort* __restrict__ Kb,
    const ushort* __restrict__ Vt, ushort* __restrict__ Ob)
{
  __shared__ __align__(16) ushort Pb[4][32*40];   // per-wave P [q][kv], stride 40
  __shared__ __align__(16) ushort OT[4][32*72];   // per-wave epilogue transpose
  const int t = threadIdx.x, l = t & 63, w = t >> 6;
  const int bid = blockIdx.x;
  const int x = bid & 7, i0 = bid >> 3;
  const int bh = x*16 + (i0 >> 3), j = i0 & 7;     // bh clustered per XCD
  int qt;
  if      (w == 0) qt = j;
  else if (w == 1) qt = 15 - j;
  else if (w == 2) qt = 16 + j;
  else             qt = 31 - j;

  const int col = l & 31, hi = l >> 5;
  const ushort* Qp = Qb + (size_t)bh*65536;
  const ushort* Kp = Kb + (size_t)bh*65536;
  const ushort* Vp = Vt + (size_t)bh*65536;

  short8 qf[4];
  #pragma unroll
  for (int m=0;m<4;m++)
    qf[m] = *(const short8*)&Qp[(size_t)(qt*32+col)*64 + m*16 + hi*8];

  f32x16 accO0 = (f32x16)0.0f, accO1 = (f32x16)0.0f;
  float mR = -1e30f, lS = 0.0f;

  ushort* Pw = &Pb[w][0];
  const int nt = qt + 1;
  for (int kt = 0; kt < nt; ++kt) {
    short8 kf[4], vf0[2], vf1[2];
    #pragma unroll
    for (int m=0;m<4;m++)
      kf[m] = *(const short8*)&Kp[(size_t)(kt*32+col)*64 + m*16 + hi*8];
    #pragma unroll
    for (int m=0;m<2;m++) {
      vf0[m] = *(const short8*)&Vp[(size_t)col*1024      + kt*32 + m*16 + hi*8];
      vf1[m] = *(const short8*)&Vp[(size_t)(32+col)*1024 + kt*32 + m*16 + hi*8];
    }

    f32x16 s = (f32x16)0.0f;
    #pragma unroll
    for (int m=0;m<4;m++)
      s = __builtin_amdgcn_mfma_f32_32x32x16_bf16(kf[m], qf[m], s, 0, 0, 0);

    if (kt == qt) {                       // diagonal tile: causal mask
      #pragma unroll
      for (int r=0;r<16;r++) {
        int kvl = (r&3) + ((r>>2)<<3) + 4*hi;
        s[r] = (kvl > col) ? -1e9f : s[r];
      }
    }

    float mx = s[0];
    #pragma unroll
    for (int r=1;r<16;r++) mx = fmaxf(mx, s[r]);
    mx = fmaxf(mx, __shfl_xor(mx, 32));   // combine kv-halves (lane i <-> i+32)

    if (__any(mx - mR > 8.0f)) {          // T13 defer-max (log2 units)
      float mN = fmaxf(mR, mx);
      float corr = __builtin_amdgcn_exp2f(mR - mN);
      mR = mN; lS *= corr;
      #pragma unroll
      for (int r=0;r<16;r++) { accO0[r] *= corr; accO1[r] *= corr; }
    }

    float p[16], rs = 0.0f;
    #pragma unroll
    for (int r=0;r<16;r++) { p[r] = __builtin_amdgcn_exp2f(s[r] - mR); rs += p[r]; }
    rs += __shfl_xor(rs, 32);
    lS += rs;

    // P -> per-wave LDS [q][kv] (packed pair writes), then B-fragment reads
    #pragma unroll
    for (int r2=0;r2<8;r2++) {
      int r = 2*r2;
      int kv = (r&3) + ((r>>2)<<3) + 4*hi;          // even; pair (kv, kv+1)
      *(unsigned*)&Pw[col*40 + kv] = pk2(p[r], p[r+1]);
    }
    short8 pb0 = *(const short8*)&Pw[col*40 + hi*8];        // kv 0..15 slice
    short8 pb1 = *(const short8*)&Pw[col*40 + 16 + hi*8];   // kv 16..31 slice

    accO0 = __builtin_amdgcn_mfma_f32_32x32x16_bf16(vf0[0], pb0, accO0, 0,0,0);
    accO0 = __builtin_amdgcn_mfma_f32_32x32x16_bf16(vf0[1], pb1, accO0, 0,0,0);
    accO1 = __builtin_amdgcn_mfma_f32_32x32x16_bf16(vf1[0], pb0, accO1, 0,0,0);
    accO1 = __builtin_amdgcn_mfma_f32_32x32x16_bf16(vf1[1], pb1, accO1, 0,0,0);
  }

  // epilogue: O[dv][q] regs -> LDS transpose -> coalesced global store
  float inv = 1.0f / lS;
  ushort* o = &OT[w][0];
  #pragma unroll
  for (int r2=0;r2<8;r2++) {
    int r = 2*r2;
    int dv = (r&3) + ((r>>2)<<3) + 4*hi;
    *(unsigned*)&o[col*72 + dv]      = pk2(accO0[r]*inv, accO0[r+1]*inv);
    *(unsigned*)&o[col*72 + 32 + dv] = pk2(accO1[r]*inv, accO1[r+1]*inv);
  }
  const int b = bh >> 4, h = bh & 15;
  #pragma unroll
  for (int it=0; it<4; ++it) {
    int q = it*8 + (l>>3), c8 = (l&7)*8;
    uint4 v = *(const uint4*)&o[q*72 + c8];
    int qg = qt*32 + q;
    *(uint4*)&Ob[(size_t)(b*1024+qg)*1024 + h*64 + c8] = v;
  }
}

extern "C" void kernel_launch(void* const* d_in, const int* in_sizes, int n_in,
                              void* d_out, int out_size, void* d_ws, size_t ws_size,
                              hipStream_t stream) {
  const float* query = (const float*)d_in[0];
  const float* Wq = (const float*)d_in[4];
  const float* bq = (const float*)d_in[5];
  const float* Wk = (const float*)d_in[6];
  const float* bk = (const float*)d_in[7];
  const float* Wv = (const float*)d_in[8];
  const float* bv = (const float*)d_in[9];
  const float* Wo = (const float*)d_in[10];
  const float* bo = (const float*)d_in[11];

  char* wsb = (char*)d_ws;
  ushort* Xb   = (ushort*)(wsb);                  // 16 MB
  ushort* Wqkv = (ushort*)(wsb + 16777216);       // 6 MB
  float*  Bqkv = (float*) (wsb + 23068672);       // 12 KB
  ushort* Wob  = (ushort*)(wsb + 23080960);       // 2 MB
  ushort* Qb   = (ushort*)(wsb + 25178112);       // 16 MB
  ushort* Kb   = (ushort*)(wsb + 41955328);       // 16 MB
  ushort* Vtb  = (ushort*)(wsb + 58732544);       // 16 MB  [bh][d][s]
  ushort* Ob   = (ushort*)(wsb + 75509760);       // 16 MB

  hipLaunchKernelGGL(pack_x_kern, dim3(4096), dim3(256), 0, stream, query, Xb);
  hipLaunchKernelGGL(pack_w_kern, dim3(1024), dim3(256), 0, stream,
                     Wq, Wk, Wv, bq, bk, bv, Wo, Wqkv, Bqkv, Wob);
  hipLaunchKernelGGL(gemm_kern<0>, dim3(64, 24), dim3(256), 0, stream,
                     Xb, Wqkv, Bqkv, Qb, Kb, Vtb, (float*)nullptr);
  hipLaunchKernelGGL(attn_kern, dim3(1024), dim3(256), 0, stream, Qb, Kb, Vtb, Ob);
  hipLaunchKernelGGL(gemm_kern<1>, dim3(64, 8), dim3(256), 0, stream,
                     Ob, Wob, bo, (ushort*)nullptr, (ushort*)nullptr, (ushort*)nullptr,
                     (float*)d_out);
}